// Round 6
// baseline (684.503 us; speedup 1.0000x reference)
//
#include <hip/hip_runtime.h>
#include <hip/hip_bf16.h>
#include <hip/hip_fp16.h>
#include <hip/hip_cooperative_groups.h>

namespace cg = cooperative_groups;

// Problem: B=4096, D=1024, H=8192, O=1000
//   winners[b] = argmin_h ||x_b - k_h||  (== argmax dot, k rows unit-norm)
//   output[b,o] = G[o, winners[b]]
// Single cooperative dispatch, 1024 blocks (4/CU x 256 CU, exact residency):
//   phase A: fp32->fp16 convert (x,kw) + parallel G->Gt transpose
//   phase B: fp16 MFMA gemm (BK=64, XOR-swizzled LDS), top-2 packed keys/tile
//   phase C: wave-per-row exact fp64 refinement + coalesced gather
// grid.sync() between phases. Fallback: 3-dispatch path if coop launch fails.

#define BB 4096
#define DD 1024
#define HH 8192
#define OO 1000

#define BM 128
#define BN 128
#define BK 64
#define NTILES (HH / BN)   // 64
#define GRID_BLKS 1024

typedef _Float16 f16;
typedef _Float16 f16x4 __attribute__((ext_vector_type(4)));
typedef _Float16 f16x8 __attribute__((ext_vector_type(8)));
typedef float f32x4 __attribute__((ext_vector_type(4)));

typedef __attribute__((address_space(3))) uint32_t lds_u32_t;
typedef __attribute__((address_space(1))) uint32_t glb_u32_t;

// ---- packed key: monotone(float) with low 7 bits = tile-local column ----
__device__ __forceinline__ uint32_t packkey(float v, int col) {
  uint32_t u = __float_as_uint(v);
  uint32_t mask = (uint32_t)((int32_t)u >> 31) | 0x80000000u;
  u ^= mask;                       // monotone: bigger float -> bigger uint
  return (u & 0xFFFFFF80u) | (uint32_t)col;
}
__device__ __forceinline__ float unpackval(uint32_t k) {
  uint32_t u = k & 0xFFFFFF80u;
  uint32_t mask = (k & 0x80000000u) ? 0x80000000u : 0xFFFFFFFFu;
  return __uint_as_float(u ^ mask);
}
__device__ __forceinline__ void kmerge(uint32_t& k1, uint32_t& k2,
                                       uint32_t o1, uint32_t o2) {
  uint32_t mn = min(k1, o1);
  uint32_t alt = (k1 > o1) ? k2 : o2;
  k1 = max(k1, o1);
  k2 = max(mn, alt);
}

// ================= device-side phase bodies (shared by both paths) ==========

__device__ __forceinline__ void convert_row(const float* __restrict__ src,
                                            f16* __restrict__ dst, int tid) {
  float4 v = ((const float4*)src)[tid];
  f16x4 h;
  h[0] = (f16)v.x; h[1] = (f16)v.y; h[2] = (f16)v.z; h[3] = (f16)v.w;
  *(f16x4*)(dst + 4 * tid) = h;
}

// one 32x32 transpose tile of G[O][H] -> Gt[H][O]; uses caller LDS tile[32][33]
__device__ __forceinline__ void transpose_tile(const float* __restrict__ G,
                                               float* __restrict__ Gt,
                                               float (*tile)[33],
                                               int tile_id, int tid) {
  const int h0 = (tile_id >> 5) * 32;
  const int o0 = (tile_id & 31) * 32;
  const int tx = tid & 31;
  const int ty = tid >> 5;  // 0..7
  __syncthreads();
#pragma unroll
  for (int j = 0; j < 4; ++j) {
    int o = o0 + ty + j * 8;
    if (o < OO) tile[ty + j * 8][tx] = G[(size_t)o * HH + h0 + tx];
  }
  __syncthreads();
#pragma unroll
  for (int j = 0; j < 4; ++j) {
    int o = o0 + tx;
    int h = h0 + ty + j * 8;
    if (o < OO) Gt[(size_t)h * OO + o] = tile[tx][ty + j * 8];
  }
}

// full 128x128 gemm tile (bx, by) + top-2 packed-key epilogue.
// sA/sB: 16 KB each, mk: uint2[128][2]. BK=64, XOR-swizzled LDS chunks.
__device__ __forceinline__ void gemm_tile(const f16* __restrict__ A,
                                          const f16* __restrict__ Bt,
                                          uint2* __restrict__ pk,
                                          f16* sA, f16* sB, uint2 (*mk)[2],
                                          int bx, int by, int tid) {
  const int w = tid >> 6;
  const int L = tid & 63;
  const int m0 = by * BM;
  const int n0 = bx * BN;
  const int rm = (w >> 1) * 64;
  const int cn = (w & 1) * 64;

  f32x4 acc[4][4];
#pragma unroll
  for (int i = 0; i < 4; ++i)
#pragma unroll
    for (int j = 0; j < 4; ++j) {
      acc[i][j][0] = 0.f; acc[i][j][1] = 0.f; acc[i][j][2] = 0.f; acc[i][j][3] = 0.f;
    }

  const int lm = L & 15;
  const int lq = L >> 4;

  const int r0 = tid >> 3;
  const int sc0 = ((tid & 7) ^ (r0 & 7)) * 8;  // swizzled source k-offset
  const f16* pA = A + (size_t)(m0 + r0) * DD + sc0;
  const f16* pB = Bt + (size_t)(n0 + r0) * DD + sc0;
  const size_t rstep = (size_t)32 * DD;

  const int swz = (lm & 7);
  const int ra0 = (rm + lm) * BK + ((0 * 4 + lq) ^ swz) * 8;
  const int ra1 = (rm + lm) * BK + ((1 * 4 + lq) ^ swz) * 8;
  const int rb0 = (cn + lm) * BK + ((0 * 4 + lq) ^ swz) * 8;
  const int rb1 = (cn + lm) * BK + ((1 * 4 + lq) ^ swz) * 8;

  for (int kt = 0; kt < DD / BK; ++kt) {
    __syncthreads();
#pragma unroll
    for (int j = 0; j < 4; ++j) {
      __builtin_amdgcn_global_load_lds((const glb_u32_t*)(pA + j * rstep),
                                       (lds_u32_t*)(sA + (tid + j * 256) * 8), 16, 0, 0);
      __builtin_amdgcn_global_load_lds((const glb_u32_t*)(pB + j * rstep),
                                       (lds_u32_t*)(sB + (tid + j * 256) * 8), 16, 0, 0);
    }
    pA += BK; pB += BK;
    __syncthreads();

    f16x8 af[4], bf[4];
#pragma unroll
    for (int i = 0; i < 4; ++i)
      af[i] = *(const f16x8*)(sA + ra0 + i * 16 * BK);
#pragma unroll
    for (int j = 0; j < 4; ++j)
      bf[j] = *(const f16x8*)(sB + rb0 + j * 16 * BK);
#pragma unroll
    for (int i = 0; i < 4; ++i)
#pragma unroll
      for (int j = 0; j < 4; ++j)
        acc[i][j] = __builtin_amdgcn_mfma_f32_16x16x32_f16(af[i], bf[j], acc[i][j], 0, 0, 0);
#pragma unroll
    for (int i = 0; i < 4; ++i)
      af[i] = *(const f16x8*)(sA + ra1 + i * 16 * BK);
#pragma unroll
    for (int j = 0; j < 4; ++j)
      bf[j] = *(const f16x8*)(sB + rb1 + j * 16 * BK);
#pragma unroll
    for (int i = 0; i < 4; ++i)
#pragma unroll
      for (int j = 0; j < 4; ++j)
        acc[i][j] = __builtin_amdgcn_mfma_f32_16x16x32_f16(af[i], bf[j], acc[i][j], 0, 0, 0);
  }

  // per-row top-2 over 128 cols (packed keys). C/D: col=lane&15, row=lq*4+reg.
  const int col0 = cn + lm;
#pragma unroll
  for (int i = 0; i < 4; ++i) {
#pragma unroll
    for (int r = 0; r < 4; ++r) {
      uint32_t k1 = 0, k2 = 0;
#pragma unroll
      for (int j = 0; j < 4; ++j) {
        uint32_t kj = packkey(acc[i][j][r], col0 + j * 16);
        if (kj > k1) { k2 = k1; k1 = kj; }
        else k2 = max(k2, kj);
      }
#pragma unroll
      for (int msk = 1; msk < 16; msk <<= 1) {
        uint32_t o1 = (uint32_t)__shfl_xor((int)k1, msk, 64);
        uint32_t o2 = (uint32_t)__shfl_xor((int)k2, msk, 64);
        kmerge(k1, k2, o1, o2);
      }
      if (lm == 0) {
        int rl = rm + i * 16 + lq * 4 + r;
        mk[rl][w & 1] = make_uint2(k1, k2);
      }
    }
  }
  __syncthreads();
  if (tid < 128) {
    uint2 a = mk[tid][0], b = mk[tid][1];
    kmerge(a.x, a.y, b.x, b.y);
    pk[(size_t)(m0 + tid) * NTILES + bx] = a;
  }
  __syncthreads();  // mk reads done before any LDS reuse
}

// wave-per-row exact fp64 refinement + gather for row b (no block barriers)
__device__ __forceinline__ void select_row(const float* __restrict__ x,
                                           const float* __restrict__ kw,
                                           const uint2* __restrict__ pk,
                                           const float* __restrict__ Gt,
                                           const float* __restrict__ G,
                                           float* __restrict__ out,
                                           float* __restrict__ out_w,
                                           int b, int L) {
  const float4* x4 = (const float4*)(x + (size_t)b * DD);
  float4 xv[4];
#pragma unroll
  for (int j = 0; j < 4; ++j) xv[j] = x4[L + 64 * j];

  uint2 kp = pk[(size_t)b * NTILES + L];

  double x2 = 0.0;
#pragma unroll
  for (int j = 0; j < 4; ++j)
    x2 += (double)xv[j].x * xv[j].x + (double)xv[j].y * xv[j].y +
          (double)xv[j].z * xv[j].z + (double)xv[j].w * xv[j].w;
#pragma unroll
  for (int msk = 1; msk < 64; msk <<= 1) x2 += __shfl_xor(x2, msk, 64);

  uint32_t m = kp.x;
#pragma unroll
  for (int msk = 1; msk < 64; msk <<= 1)
    m = max(m, (uint32_t)__shfl_xor((int)m, msk, 64));
  const uint32_t thrk = packkey(unpackval(m) - 0.01f, 0);  // margin >> fp16 err

  unsigned long long cand1 = __ballot(kp.x >= thrk);
  unsigned long long cand2 = __ballot(kp.y >= thrk);

  double best = 1e300;
  int bestc = 0x7fffffff;
#pragma unroll 1
  for (int pass = 0; pass < 2; ++pass) {
    unsigned long long bits = (pass == 0) ? cand1 : cand2;
    uint32_t mykey = (pass == 0) ? kp.x : kp.y;
    while (bits) {
      int t = __ffsll((long long)bits) - 1;
      bits &= bits - 1;
      uint32_t kbt = (uint32_t)__shfl((int)mykey, t, 64);
      int col = t * 128 + (int)(kbt & 127u);
      const float4* k4 = (const float4*)(kw + (size_t)col * DD);
      double dot = 0.0, w2 = 0.0;
#pragma unroll
      for (int j = 0; j < 4; ++j) {
        float4 wv = k4[L + 64 * j];
        dot += (double)xv[j].x * wv.x + (double)xv[j].y * wv.y +
               (double)xv[j].z * wv.z + (double)xv[j].w * wv.w;
        w2 += (double)wv.x * wv.x + (double)wv.y * wv.y +
              (double)wv.z * wv.z + (double)wv.w * wv.w;
      }
#pragma unroll
      for (int msk = 1; msk < 64; msk <<= 1) {
        dot += __shfl_xor(dot, msk, 64);
        w2 += __shfl_xor(w2, msk, 64);
      }
      double sq = x2 + w2 - 2.0 * dot;
      if (sq < best || (sq == best && col < bestc)) { best = sq; bestc = col; }
    }
  }

  if (L == 0) out_w[b] = (float)bestc;
  if (Gt != nullptr) {
    const float4* gsrc = (const float4*)(Gt + (size_t)bestc * OO);
    float4* gdst = (float4*)(out + (size_t)b * OO);
#pragma unroll
    for (int j = 0; j < 4; ++j) {
      int q = L + 64 * j;
      if (q < OO / 4) gdst[q] = gsrc[q];
    }
  } else {
#pragma unroll 1
    for (int j = 0; j < 16; ++j) {
      int o = L + 64 * j;
      if (o < OO) out[(size_t)b * OO + o] = G[(size_t)o * HH + bestc];
    }
  }
}

// ====================== cooperative mega-kernel =============================
__global__ __launch_bounds__(256, 4) void mega_kernel(
    const float* __restrict__ x, const float* __restrict__ kw,
    const float* __restrict__ G,
    f16* __restrict__ xh, f16* __restrict__ kh, float* __restrict__ Gt,
    uint2* __restrict__ pk, float* __restrict__ out, float* __restrict__ out_w) {
  __shared__ __align__(16) char smem[34816];  // 16K sA + 16K sB + 2K mk
  f16* sA = (f16*)smem;
  f16* sB = (f16*)(smem + 16384);
  uint2 (*mk)[2] = (uint2(*)[2])(smem + 32768);
  float (*ttile)[33] = (float(*)[33])smem;

  const int bid = blockIdx.x;
  const int tid = threadIdx.x;
  cg::grid_group grid = cg::this_grid();

  // ---- phase A: convert (12 rows/block) + transpose (8 tiles/block) ----
#pragma unroll 1
  for (int r = bid; r < BB + HH; r += GRID_BLKS) {
    const float* src = (r < BB) ? (x + (size_t)r * DD) : (kw + (size_t)(r - BB) * DD);
    f16* dst = (r < BB) ? (xh + (size_t)r * DD) : (kh + (size_t)(r - BB) * DD);
    convert_row(src, dst, tid);
  }
  if (Gt != nullptr) {
#pragma unroll 1
    for (int t = bid; t < 8192; t += GRID_BLKS)
      transpose_tile(G, Gt, ttile, t, tid);
  }
  __threadfence();
  grid.sync();

  // ---- phase B: gemm, exactly 2 tiles/block ----
#pragma unroll 1
  for (int tt = 0; tt < 2; ++tt) {
    int t = bid + tt * GRID_BLKS;   // 0..2047
    gemm_tile(xh, kh, pk, sA, sB, mk, t & 63, t >> 6, tid);
  }
  __threadfence();
  grid.sync();

  // ---- phase C: select + gather, 4 rows/block (one per wave) ----
  select_row(x, kw, pk, Gt, G, out, out_w, bid * 4 + (tid >> 6), tid & 63);
}

// ====================== 3-dispatch fallback path ============================
__global__ __launch_bounds__(256) void cvt_kernel(
    const float* __restrict__ x, const float* __restrict__ kw,
    f16* __restrict__ xh, f16* __restrict__ kh,
    const float* __restrict__ G, float* __restrict__ Gt) {
  const int blk = blockIdx.x;
  const int tid = threadIdx.x;
  __shared__ float tile[32][33];
  if (blk < BB + HH) {
    const float* src = (blk < BB) ? (x + (size_t)blk * DD)
                                  : (kw + (size_t)(blk - BB) * DD);
    f16* dst = (blk < BB) ? (xh + (size_t)blk * DD)
                          : (kh + (size_t)(blk - BB) * DD);
    convert_row(src, dst, tid);
  } else {
    transpose_tile(G, Gt, tile, blk - (BB + HH), tid);
  }
}

__global__ __launch_bounds__(256) void gemm_top2(
    const f16* __restrict__ A, const f16* __restrict__ Bt,
    uint2* __restrict__ pk) {
  __shared__ __align__(16) f16 sA[BM * BK];
  __shared__ __align__(16) f16 sB[BN * BK];
  __shared__ uint2 mk[128][2];
  gemm_tile(A, Bt, pk, sA, sB, mk, blockIdx.x, blockIdx.y, threadIdx.x);
}

__global__ __launch_bounds__(256) void select_kernel(
    const float* __restrict__ x, const float* __restrict__ kw,
    const uint2* __restrict__ pk, const float* __restrict__ Gt,
    const float* __restrict__ G, float* __restrict__ out,
    float* __restrict__ out_w) {
  select_row(x, kw, pk, Gt, G, out, out_w,
             blockIdx.x * 4 + (threadIdx.x >> 6), threadIdx.x & 63);
}

extern "C" void kernel_launch(void* const* d_in, const int* in_sizes, int n_in,
                              void* d_out, int out_size, void* d_ws, size_t ws_size,
                              hipStream_t stream) {
  const float* x  = (const float*)d_in[0];  // [4096][1024]
  const float* kw = (const float*)d_in[1];  // [8192][1024]
  const float* gw = (const float*)d_in[2];  // [1000][8192]
  float* out = (float*)d_out;               // [4096*1000] output ++ [4096] winners
  float* out_w = out + (size_t)BB * OO;

  const size_t MB = 1024 * 1024;
  char* ws = (char*)d_ws;
  f16*    xh = (f16*)(ws);                     // 8 MB
  f16*    kh = (f16*)(ws + 8 * MB);            // 16 MB
  uint2*  pk = (uint2*)(ws + 24 * MB);         // 2 MB
  float*  Gt = (float*)(ws + 26 * MB + 65536); // 32.77 MB
  const size_t need = 26 * MB + 65536 + sizeof(float) * (size_t)HH * OO;
  float* GtArg = (ws_size >= need) ? Gt : nullptr;

  void* kargs[] = {(void*)&x, (void*)&kw, (void*)&gw, (void*)&xh, (void*)&kh,
                   (void*)&GtArg, (void*)&pk, (void*)&out, (void*)&out_w};
  hipError_t e = hipLaunchCooperativeKernel((void*)mega_kernel, dim3(GRID_BLKS),
                                            dim3(256), kargs, 0, stream);
  if (e != hipSuccess) {
    // fallback: 3 dependent dispatches (same device code paths)
    int cvt_blocks = BB + HH + (GtArg ? 8192 : 0);
    cvt_kernel<<<cvt_blocks, 256, 0, stream>>>(x, kw, xh, kh, gw, GtArg);
    dim3 g(HH / BN, BB / BM);
    gemm_top2<<<g, 256, 0, stream>>>(xh, kh, pk);
    select_kernel<<<BB / 4, 256, 0, stream>>>(x, kw, pk, GtArg, gw, out, out_w);
  }
}

// Round 7
// 252.353 us; speedup vs baseline: 2.7125x; 2.7125x over previous
//
#include <hip/hip_runtime.h>
#include <hip/hip_bf16.h>
#include <hip/hip_fp16.h>

// Problem: B=4096, D=1024, H=8192, O=1000
//   winners[b] = argmin_h ||x_b - k_h||  (== argmax dot, k rows unit-norm)
//   output[b,o] = G[o, winners[b]]
// Pipeline (3 dispatches), measured fixed replay overhead ~75 us (R6 coop probe):
//   1) cvt: fp32->fp16 for x,kw (4 rows/block)
//   2) gemm_top2: fp16 MFMA scores (BK=64, XOR-swizzled LDS), top-2 packed keys
//      per (row, 128-col tile) + 2048 tail blocks doing the G->Gt transpose
//      (rides the latency-bound gemm's bandwidth shadow)
//   3) select: wave-per-row exact fp64 refinement (no barriers) + fused gather.

#define BB 4096
#define DD 1024
#define HH 8192
#define OO 1000

#define BM 128
#define BN 128
#define BK 64
#define NTILES (HH / BN)   // 64

typedef _Float16 f16;
typedef _Float16 f16x4 __attribute__((ext_vector_type(4)));
typedef _Float16 f16x8 __attribute__((ext_vector_type(8)));
typedef float f32x4 __attribute__((ext_vector_type(4)));

typedef __attribute__((address_space(3))) uint32_t lds_u32_t;
typedef __attribute__((address_space(1))) uint32_t glb_u32_t;

// ---- packed key: monotone(float) with low 7 bits = tile-local column ----
__device__ __forceinline__ uint32_t packkey(float v, int col) {
  uint32_t u = __float_as_uint(v);
  uint32_t mask = (uint32_t)((int32_t)u >> 31) | 0x80000000u;
  u ^= mask;                       // monotone: bigger float -> bigger uint
  return (u & 0xFFFFFF80u) | (uint32_t)col;
}
__device__ __forceinline__ float unpackval(uint32_t k) {
  uint32_t u = k & 0xFFFFFF80u;
  uint32_t mask = (k & 0x80000000u) ? 0x80000000u : 0xFFFFFFFFu;
  return __uint_as_float(u ^ mask);
}
__device__ __forceinline__ void kmerge(uint32_t& k1, uint32_t& k2,
                                       uint32_t o1, uint32_t o2) {
  uint32_t mn = min(k1, o1);
  uint32_t alt = (k1 > o1) ? k2 : o2;
  k1 = max(k1, o1);
  k2 = max(mn, alt);
}

// ---------------- cvt: fp32 -> fp16, 4 rows per block ----------------
__global__ __launch_bounds__(256) void cvt_kernel(
    const float* __restrict__ x, const float* __restrict__ kw,
    f16* __restrict__ xh, f16* __restrict__ kh) {
  const int tid = threadIdx.x;
#pragma unroll
  for (int i = 0; i < 4; ++i) {
    int r = blockIdx.x * 4 + i;   // 0 .. BB+HH-1
    const float* src = (r < BB) ? (x + (size_t)r * DD)
                                : (kw + (size_t)(r - BB) * DD);
    f16* dst = (r < BB) ? (xh + (size_t)r * DD)
                        : (kh + (size_t)(r - BB) * DD);
    float4 v = ((const float4*)src)[tid];
    f16x4 h;
    h[0] = (f16)v.x; h[1] = (f16)v.y; h[2] = (f16)v.z; h[3] = (f16)v.w;
    *(f16x4*)(dst + 4 * tid) = h;
  }
}

// ---------------- GEMM (scores) + top-2 keys + transpose tail ---------------
// blocks [0,2048): 128x128 C-tile (bx = t&63, by = t>>6), BK=64 K-loop,
//   XOR-swizzled LDS (writer lane-linear, reader conflict-free), top-2 packed
//   keys per row over the tile's 128 columns.
// blocks [2048,4096): 4 parallel 32x32 transpose tiles of G[O][H] -> Gt[H][O].
__global__ __launch_bounds__(256) void gemm_top2(
    const f16* __restrict__ A, const f16* __restrict__ Bt,
    uint2* __restrict__ pk,
    const float* __restrict__ G, float* __restrict__ Gt) {
  __shared__ __align__(16) f16 sA[BM * BK];  // 16 KB
  __shared__ __align__(16) f16 sB[BN * BK];  // 16 KB
  __shared__ uint2 mk[128][2];               // 2 KB

  const int tid = threadIdx.x;
  const int t = blockIdx.x;

  if (t >= 2048) {
    // -------- transpose tail: 4 tiles per block --------
    if (Gt == nullptr) return;
    float (*tile)[33] = (float(*)[33])sA;
    const int tx = tid & 31;
    const int ty = tid >> 5;  // 0..7
#pragma unroll 1
    for (int j4 = 0; j4 < 4; ++j4) {
      int tile_id = (t - 2048) * 4 + j4;   // 0..8191
      int h0 = (tile_id >> 5) * 32;
      int o0 = (tile_id & 31) * 32;
      __syncthreads();
#pragma unroll
      for (int j = 0; j < 4; ++j) {
        int o = o0 + ty + j * 8;
        if (o < OO) tile[ty + j * 8][tx] = G[(size_t)o * HH + h0 + tx];
      }
      __syncthreads();
#pragma unroll
      for (int j = 0; j < 4; ++j) {
        int o = o0 + tx;
        int h = h0 + ty + j * 8;
        if (o < OO) Gt[(size_t)h * OO + o] = tile[tx][ty + j * 8];
      }
    }
    return;
  }

  const int w = tid >> 6;       // wave 0..3
  const int L = tid & 63;       // lane
  const int m0 = (t >> 6) * BM;
  const int n0 = (t & 63) * BN;
  const int rm = (w >> 1) * 64;  // wave row base within tile
  const int cn = (w & 1) * 64;   // wave col base within tile

  f32x4 acc[4][4];
#pragma unroll
  for (int i = 0; i < 4; ++i)
#pragma unroll
    for (int j = 0; j < 4; ++j) {
      acc[i][j][0] = 0.f; acc[i][j][1] = 0.f; acc[i][j][2] = 0.f; acc[i][j][3] = 0.f;
    }

  const int lm = L & 15;    // fragment row within 16
  const int lq = L >> 4;    // quad -> k-offset lq*8

  // staging: thread owns LDS chunks tid + j*256, j=0..3 (chunk = 16B = 8 f16)
  const int r0 = tid >> 3;
  const int sc0 = ((tid & 7) ^ (r0 & 7)) * 8;  // swizzled source k-offset (f16)
  const f16* pA = A + (size_t)(m0 + r0) * DD + sc0;
  const f16* pB = Bt + (size_t)(n0 + r0) * DD + sc0;
  const size_t rstep = (size_t)32 * DD;  // +32 rows per j

  // fragment read base: row*BK + ((khalf*4+lq) ^ (row&7))*8 ; row&7 == lm&7
  const int swz = (lm & 7);
  const int ra0 = (rm + lm) * BK + ((0 * 4 + lq) ^ swz) * 8;
  const int ra1 = (rm + lm) * BK + ((1 * 4 + lq) ^ swz) * 8;
  const int rb0 = (cn + lm) * BK + ((0 * 4 + lq) ^ swz) * 8;
  const int rb1 = (cn + lm) * BK + ((1 * 4 + lq) ^ swz) * 8;

  for (int kt = 0; kt < DD / BK; ++kt) {
    __syncthreads();  // prev compute done before overwriting LDS
#pragma unroll
    for (int j = 0; j < 4; ++j) {
      __builtin_amdgcn_global_load_lds((const glb_u32_t*)(pA + j * rstep),
                                       (lds_u32_t*)(sA + (tid + j * 256) * 8), 16, 0, 0);
      __builtin_amdgcn_global_load_lds((const glb_u32_t*)(pB + j * rstep),
                                       (lds_u32_t*)(sB + (tid + j * 256) * 8), 16, 0, 0);
    }
    pA += BK; pB += BK;
    __syncthreads();  // drains vmcnt before use

    f16x8 af[4], bf[4];
    // k-half 0
#pragma unroll
    for (int i = 0; i < 4; ++i)
      af[i] = *(const f16x8*)(sA + ra0 + i * 16 * BK);
#pragma unroll
    for (int j = 0; j < 4; ++j)
      bf[j] = *(const f16x8*)(sB + rb0 + j * 16 * BK);
#pragma unroll
    for (int i = 0; i < 4; ++i)
#pragma unroll
      for (int j = 0; j < 4; ++j)
        acc[i][j] = __builtin_amdgcn_mfma_f32_16x16x32_f16(af[i], bf[j], acc[i][j], 0, 0, 0);
    // k-half 1
#pragma unroll
    for (int i = 0; i < 4; ++i)
      af[i] = *(const f16x8*)(sA + ra1 + i * 16 * BK);
#pragma unroll
    for (int j = 0; j < 4; ++j)
      bf[j] = *(const f16x8*)(sB + rb1 + j * 16 * BK);
#pragma unroll
    for (int i = 0; i < 4; ++i)
#pragma unroll
      for (int j = 0; j < 4; ++j)
        acc[i][j] = __builtin_amdgcn_mfma_f32_16x16x32_f16(af[i], bf[j], acc[i][j], 0, 0, 0);
  }

  // Epilogue: per-row top-2 over 128 cols (packed keys).
  // C/D layout (16x16x32): col = lane&15, row = (lane>>4)*4 + reg.
  const int col0 = cn + lm;
#pragma unroll
  for (int i = 0; i < 4; ++i) {
#pragma unroll
    for (int r = 0; r < 4; ++r) {
      uint32_t k1 = 0, k2 = 0;
#pragma unroll
      for (int j = 0; j < 4; ++j) {
        uint32_t kj = packkey(acc[i][j][r], col0 + j * 16);
        if (kj > k1) { k2 = k1; k1 = kj; }
        else k2 = max(k2, kj);
      }
#pragma unroll
      for (int msk = 1; msk < 16; msk <<= 1) {
        uint32_t o1 = (uint32_t)__shfl_xor((int)k1, msk, 64);
        uint32_t o2 = (uint32_t)__shfl_xor((int)k2, msk, 64);
        kmerge(k1, k2, o1, o2);
      }
      if (lm == 0) {
        int rl = rm + i * 16 + lq * 4 + r;
        mk[rl][w & 1] = make_uint2(k1, k2);
      }
    }
  }
  __syncthreads();
  if (tid < 128) {
    uint2 a = mk[tid][0], b = mk[tid][1];
    kmerge(a.x, a.y, b.x, b.y);
    pk[(size_t)(m0 + tid) * NTILES + (t & 63)] = a;
  }
}

// ------- select: wave-per-row exact fp64 refinement + fused gather ----------
// One 64-lane wave per x-row; 4 rows per 256-thread block. No __syncthreads.
__global__ __launch_bounds__(256) void select_kernel(
    const float* __restrict__ x, const float* __restrict__ kw,
    const uint2* __restrict__ pk,
    const float* __restrict__ Gt, const float* __restrict__ G,
    float* __restrict__ out, float* __restrict__ out_w) {
  const int b = blockIdx.x * 4 + (threadIdx.x >> 6);
  const int L = threadIdx.x & 63;

  // x row: 16 floats/lane (4 x float4, coalesced)
  const float4* x4 = (const float4*)(x + (size_t)b * DD);
  float4 xv[4];
#pragma unroll
  for (int j = 0; j < 4; ++j) xv[j] = x4[L + 64 * j];

  // keys of tile L (top-2, packed, k1>=k2)
  uint2 kp = pk[(size_t)b * NTILES + L];

  // x2 in fp64 (xor-reduce -> all lanes hold total)
  double x2 = 0.0;
#pragma unroll
  for (int j = 0; j < 4; ++j)
    x2 += (double)xv[j].x * xv[j].x + (double)xv[j].y * xv[j].y +
          (double)xv[j].z * xv[j].z + (double)xv[j].w * xv[j].w;
#pragma unroll
  for (int msk = 1; msk < 64; msk <<= 1) x2 += __shfl_xor(x2, msk, 64);

  // global max key -> margin threshold
  uint32_t m = kp.x;
#pragma unroll
  for (int msk = 1; msk < 64; msk <<= 1)
    m = max(m, (uint32_t)__shfl_xor((int)m, msk, 64));
  const uint32_t thrk = packkey(unpackval(m) - 0.01f, 0);  // margin >> fp16 err

  unsigned long long cand1 = __ballot(kp.x >= thrk);
  unsigned long long cand2 = __ballot(kp.y >= thrk);

  double best = 1e300;
  int bestc = 0x7fffffff;
#pragma unroll 1
  for (int pass = 0; pass < 2; ++pass) {
    unsigned long long bits = (pass == 0) ? cand1 : cand2;
    uint32_t mykey = (pass == 0) ? kp.x : kp.y;
    while (bits) {
      int tt = __ffsll((long long)bits) - 1;   // candidate's tile = lane tt
      bits &= bits - 1;
      uint32_t kbt = (uint32_t)__shfl((int)mykey, tt, 64);
      int col = tt * 128 + (int)(kbt & 127u);
      const float4* k4 = (const float4*)(kw + (size_t)col * DD);
      double dot = 0.0, w2 = 0.0;
#pragma unroll
      for (int j = 0; j < 4; ++j) {
        float4 wv = k4[L + 64 * j];
        dot += (double)xv[j].x * wv.x + (double)xv[j].y * wv.y +
               (double)xv[j].z * wv.z + (double)xv[j].w * wv.w;
        w2 += (double)wv.x * wv.x + (double)wv.y * wv.y +
              (double)wv.z * wv.z + (double)wv.w * wv.w;
      }
#pragma unroll
      for (int msk = 1; msk < 64; msk <<= 1) {
        dot += __shfl_xor(dot, msk, 64);
        w2 += __shfl_xor(w2, msk, 64);
      }
      double sq = x2 + w2 - 2.0 * dot;   // identical on all lanes
      if (sq < best || (sq == best && col < bestc)) { best = sq; bestc = col; }
    }
  }

  if (L == 0) out_w[b] = (float)bestc;  // winners as fp32 (flat fp32 buffer)
  if (Gt != nullptr) {
    // coalesced gather: out[b,:] = Gt[bestc,:]  (wave-uniform bestc)
    const float4* gsrc = (const float4*)(Gt + (size_t)bestc * OO);
    float4* gdst = (float4*)(out + (size_t)b * OO);
#pragma unroll
    for (int j = 0; j < 4; ++j) {
      int q = L + 64 * j;
      if (q < OO / 4) gdst[q] = gsrc[q];
    }
  } else {
    // fallback: strided gather from G
#pragma unroll 1
    for (int j = 0; j < 16; ++j) {
      int o = L + 64 * j;
      if (o < OO) out[(size_t)b * OO + o] = G[(size_t)o * HH + bestc];
    }
  }
}

extern "C" void kernel_launch(void* const* d_in, const int* in_sizes, int n_in,
                              void* d_out, int out_size, void* d_ws, size_t ws_size,
                              hipStream_t stream) {
  const float* x  = (const float*)d_in[0];  // [4096][1024]
  const float* kw = (const float*)d_in[1];  // [8192][1024]
  const float* gw = (const float*)d_in[2];  // [1000][8192]
  float* out = (float*)d_out;               // [4096*1000] output ++ [4096] winners
  float* out_w = out + (size_t)BB * OO;

  const size_t MB = 1024 * 1024;
  char* ws = (char*)d_ws;
  f16*    xh = (f16*)(ws);                     // 8 MB
  f16*    kh = (f16*)(ws + 8 * MB);            // 16 MB
  uint2*  pk = (uint2*)(ws + 24 * MB);         // 2 MB
  float*  Gt = (float*)(ws + 26 * MB + 65536); // 32.77 MB
  const size_t need = 26 * MB + 65536 + sizeof(float) * (size_t)HH * OO;
  float* GtArg = (ws_size >= need) ? Gt : nullptr;

  // 1) fp32 -> fp16 (4 rows/block, 3072 blocks)
  cvt_kernel<<<(BB + HH) / 4, 256, 0, stream>>>(x, kw, xh, kh);

  // 2) fp16 MFMA GEMM + top-2 keys; 2048 transpose tail blocks ride its shadow
  int gemm_blocks = 2048 + (GtArg ? 2048 : 0);
  gemm_top2<<<gemm_blocks, 256, 0, stream>>>(xh, kh, pk, gw, GtArg);

  // 3) wave-per-row exact fp64 refinement -> winners, fused coalesced gather
  select_kernel<<<BB / 4, 256, 0, stream>>>(x, kw, pk, GtArg, gw, out, out_w);
}

// Round 8
// 221.071 us; speedup vs baseline: 3.0963x; 1.1415x over previous
//
#include <hip/hip_runtime.h>
#include <hip/hip_bf16.h>
#include <hip/hip_fp16.h>

// Problem: B=4096, D=1024, H=8192, O=1000
//   winners[b] = argmin_h ||x_b - k_h||  (== argmax dot, k rows unit-norm)
//   output[b,o] = G[o, winners[b]]
// Pipeline (3 dispatches; measured fixed replay overhead ~75 us, R6 coop probe):
//   1) cvt: fp32 -> fp8(e4m3) for x,kw (4 rows/block) + parallel G->Gt transpose
//   2) gemm_top2: fp8 MFMA scores (16x16x32_fp8_fp8, BK=64, 16B-granular
//      XOR-swizzled LDS, conflict-free ds_read_b64), top-2 packed keys per
//      (row, 64-col half-tile) -> uint4 per (row, 128-tile)
//   3) select: wave-per-row exact fp64 refinement (margin 0.35 >> fp8 dot err
//      ~0.05) + fused coalesced gather.

#define BB 4096
#define DD 1024
#define HH 8192
#define OO 1000

#define BM 128
#define BN 128
#define BK 64          // bytes == elements (fp8)
#define NTILES (HH / BN)   // 64

typedef _Float16 f16;
typedef float f32x4 __attribute__((ext_vector_type(4)));

typedef __attribute__((address_space(3))) uint32_t lds_u32_t;
typedef __attribute__((address_space(1))) uint32_t glb_u32_t;

// ---- packed key: monotone(float) with low 7 bits = tile-local column ----
__device__ __forceinline__ uint32_t packkey(float v, int col) {
  uint32_t u = __float_as_uint(v);
  uint32_t mask = (uint32_t)((int32_t)u >> 31) | 0x80000000u;
  u ^= mask;                       // monotone: bigger float -> bigger uint
  return (u & 0xFFFFFF80u) | (uint32_t)col;
}
__device__ __forceinline__ float unpackval(uint32_t k) {
  uint32_t u = k & 0xFFFFFF80u;
  uint32_t mask = (k & 0x80000000u) ? 0x80000000u : 0xFFFFFFFFu;
  return __uint_as_float(u ^ mask);
}
__device__ __forceinline__ void kmerge(uint32_t& k1, uint32_t& k2,
                                       uint32_t o1, uint32_t o2) {
  uint32_t mn = min(k1, o1);
  uint32_t alt = (k1 > o1) ? k2 : o2;
  k1 = max(k1, o1);
  k2 = max(mn, alt);
}

// -------- cvt: fp32 -> fp8 e4m3 (4 rows/block) + parallel transpose ---------
// blocks [0, 3072): 4 rows each of x (rows 0..BB-1) then kw (rows BB..BB+HH-1)
// blocks [3072, 3072+2048): 4 parallel 32x32 transpose tiles of G -> Gt
__global__ __launch_bounds__(256) void cvt_kernel(
    const float* __restrict__ x, const float* __restrict__ kw,
    uint8_t* __restrict__ xq, uint8_t* __restrict__ kq,
    const float* __restrict__ G, float* __restrict__ Gt) {
  const int tid = threadIdx.x;
  const int blk = blockIdx.x;
  __shared__ float tile[32][33];
  if (blk < (BB + HH) / 4) {
#pragma unroll
    for (int i = 0; i < 4; ++i) {
      int r = blk * 4 + i;
      const float* src = (r < BB) ? (x + (size_t)r * DD)
                                  : (kw + (size_t)(r - BB) * DD);
      uint8_t* dst = (r < BB) ? (xq + (size_t)r * DD)
                              : (kq + (size_t)(r - BB) * DD);
      float4 v = ((const float4*)src)[tid];
      int p = 0;
      p = __builtin_amdgcn_cvt_pk_fp8_f32(v.x, v.y, p, false);  // bytes 0,1
      p = __builtin_amdgcn_cvt_pk_fp8_f32(v.z, v.w, p, true);   // bytes 2,3
      ((int*)dst)[tid] = p;
    }
  } else {
    if (Gt == nullptr) return;
    const int tb = blk - (BB + HH) / 4;
    const int tx = tid & 31;
    const int ty = tid >> 5;  // 0..7
#pragma unroll 1
    for (int j4 = 0; j4 < 4; ++j4) {
      int tile_id = tb * 4 + j4;       // 0..8191
      int h0 = (tile_id >> 5) * 32;
      int o0 = (tile_id & 31) * 32;
      __syncthreads();
#pragma unroll
      for (int j = 0; j < 4; ++j) {
        int o = o0 + ty + j * 8;
        if (o < OO) tile[ty + j * 8][tx] = G[(size_t)o * HH + h0 + tx];
      }
      __syncthreads();
#pragma unroll
      for (int j = 0; j < 4; ++j) {
        int o = o0 + tx;
        int h = h0 + ty + j * 8;
        if (o < OO) Gt[(size_t)h * OO + o] = tile[tx][ty + j * 8];
      }
    }
  }
}

// ---------------- GEMM (fp8 scores) + top-2 keys per half-tile --------------
// A = xq [B][D] fp8, Bt = kq [H][D] fp8 (NT). Block: 128x128 C-tile, BK=64
// (16 K-iters, 32 MFMA + 16 ds_read_b64 per iter, 4 global_load_lds/iter).
// LDS swizzle at 16B granularity: LDS 16B-chunk (row, c16) holds source chunk
// c16 ^ ((row>>1)&3). Writer (global_load_lds) stays lane-linear in LDS with
// 16B-contiguous sources; reader (8B frags) spreads conflict-free (4 rounds).
__global__ __launch_bounds__(256) void gemm_top2(
    const uint8_t* __restrict__ A, const uint8_t* __restrict__ Bt,
    uint4* __restrict__ pk) {
  __shared__ __align__(16) uint8_t sA[BM * BK];  // 8 KB
  __shared__ __align__(16) uint8_t sB[BN * BK];  // 8 KB
  __shared__ uint2 mk[128][2];                   // 2 KB

  const int tid = threadIdx.x;
  const int w = tid >> 6;       // wave 0..3
  const int L = tid & 63;       // lane
  const int m0 = blockIdx.y * BM;
  const int n0 = blockIdx.x * BN;
  const int rm = (w >> 1) * 64;  // wave row base within tile
  const int cn = (w & 1) * 64;   // wave col base within tile

  f32x4 acc[4][4];
#pragma unroll
  for (int i = 0; i < 4; ++i)
#pragma unroll
    for (int j = 0; j < 4; ++j) {
      acc[i][j][0] = 0.f; acc[i][j][1] = 0.f; acc[i][j][2] = 0.f; acc[i][j][3] = 0.f;
    }

  const int lm = L & 15;    // fragment row within 16
  const int lq = L >> 4;    // quad

  // staging: thread owns LDS 16B-chunks c0=tid (rows 0..63), c1=tid+256.
  // chunk c: row = c>>2, c16 = c&3, source 16B-chunk = c16 ^ ((row>>1)&3).
  const int c0 = tid, c1 = tid + 256;
  const int r0 = c0 >> 2, r1 = c1 >> 2;
  const int s0 = ((c0 & 3) ^ ((r0 >> 1) & 3)) * 16;
  const int s1 = ((c1 & 3) ^ ((r1 >> 1) & 3)) * 16;
  const uint8_t* pA0 = A + (size_t)(m0 + r0) * DD + s0;
  const uint8_t* pA1 = A + (size_t)(m0 + r1) * DD + s1;
  const uint8_t* pB0 = Bt + (size_t)(n0 + r0) * DD + s0;
  const uint8_t* pB1 = Bt + (size_t)(n0 + r1) * DD + s1;

  // fragment read: logical 8B-chunk q = khalf*4 + lq of row; LDS byte =
  // row*64 + ((q>>1) ^ t2)*16 + (q&1)*8, t2 = (row>>1)&3 = (lm>>1)&3.
  const int t2 = (lm >> 1) & 3;
  const int raBase = (rm + lm) * BK;
  const int rbBase = (cn + lm) * BK;
  const int off0 = (((lq >> 1)) ^ t2) * 16 + (lq & 1) * 8;        // khalf 0
  const int off1 = ((2 + (lq >> 1)) ^ t2) * 16 + (lq & 1) * 8;    // khalf 1

  for (int kt = 0; kt < DD / BK; ++kt) {
    __syncthreads();  // prev compute done before overwriting LDS
    __builtin_amdgcn_global_load_lds((const glb_u32_t*)pA0, (lds_u32_t*)(sA + c0 * 16), 16, 0, 0);
    __builtin_amdgcn_global_load_lds((const glb_u32_t*)pA1, (lds_u32_t*)(sA + c1 * 16), 16, 0, 0);
    __builtin_amdgcn_global_load_lds((const glb_u32_t*)pB0, (lds_u32_t*)(sB + c0 * 16), 16, 0, 0);
    __builtin_amdgcn_global_load_lds((const glb_u32_t*)pB1, (lds_u32_t*)(sB + c1 * 16), 16, 0, 0);
    pA0 += BK; pA1 += BK; pB0 += BK; pB1 += BK;
    __syncthreads();  // drains vmcnt before use

    long long af[4], bf[4];
    // k-half 0
#pragma unroll
    for (int i = 0; i < 4; ++i)
      af[i] = *(const long long*)(sA + raBase + i * 16 * BK + off0);
#pragma unroll
    for (int j = 0; j < 4; ++j)
      bf[j] = *(const long long*)(sB + rbBase + j * 16 * BK + off0);
#pragma unroll
    for (int i = 0; i < 4; ++i)
#pragma unroll
      for (int j = 0; j < 4; ++j)
        acc[i][j] = __builtin_amdgcn_mfma_f32_16x16x32_fp8_fp8(af[i], bf[j], acc[i][j], 0, 0, 0);
    // k-half 1
#pragma unroll
    for (int i = 0; i < 4; ++i)
      af[i] = *(const long long*)(sA + raBase + i * 16 * BK + off1);
#pragma unroll
    for (int j = 0; j < 4; ++j)
      bf[j] = *(const long long*)(sB + rbBase + j * 16 * BK + off1);
#pragma unroll
    for (int i = 0; i < 4; ++i)
#pragma unroll
      for (int j = 0; j < 4; ++j)
        acc[i][j] = __builtin_amdgcn_mfma_f32_16x16x32_fp8_fp8(af[i], bf[j], acc[i][j], 0, 0, 0);
  }

  // Epilogue: per-row top-2 over this wave's 64-col half (packed keys).
  // C/D layout (16x16x32): col = lane&15, row = (lane>>4)*4 + reg.
  const int col0 = cn + lm;
#pragma unroll
  for (int i = 0; i < 4; ++i) {
#pragma unroll
    for (int r = 0; r < 4; ++r) {
      uint32_t k1 = 0, k2 = 0;
#pragma unroll
      for (int j = 0; j < 4; ++j) {
        uint32_t kj = packkey(acc[i][j][r], col0 + j * 16);
        if (kj > k1) { k2 = k1; k1 = kj; }
        else k2 = max(k2, kj);
      }
#pragma unroll
      for (int msk = 1; msk < 16; msk <<= 1) {
        uint32_t o1 = (uint32_t)__shfl_xor((int)k1, msk, 64);
        uint32_t o2 = (uint32_t)__shfl_xor((int)k2, msk, 64);
        kmerge(k1, k2, o1, o2);
      }
      if (lm == 0) {
        int rl = rm + i * 16 + lq * 4 + r;
        mk[rl][w & 1] = make_uint2(k1, k2);
      }
    }
  }
  __syncthreads();
  if (tid < 128) {
    uint2 a = mk[tid][0], b = mk[tid][1];  // keep both halves: top-2 per 64 cols
    pk[(size_t)(m0 + tid) * NTILES + blockIdx.x] = make_uint4(a.x, a.y, b.x, b.y);
  }
}

// ------- select: wave-per-row exact fp64 refinement + fused gather ----------
// One 64-lane wave per x-row; 4 rows per 256-thread block. No __syncthreads.
__global__ __launch_bounds__(256) void select_kernel(
    const float* __restrict__ x, const float* __restrict__ kw,
    const uint4* __restrict__ pk,
    const float* __restrict__ Gt, const float* __restrict__ G,
    float* __restrict__ out, float* __restrict__ out_w) {
  const int b = blockIdx.x * 4 + (threadIdx.x >> 6);
  const int L = threadIdx.x & 63;

  // x row: 16 floats/lane (4 x float4, coalesced)
  const float4* x4 = (const float4*)(x + (size_t)b * DD);
  float4 xv[4];
#pragma unroll
  for (int j = 0; j < 4; ++j) xv[j] = x4[L + 64 * j];

  // keys of tile L: top-2 of each 64-col half (k.x>=k.y, k.z>=k.w)
  uint4 kp = pk[(size_t)b * NTILES + L];

  // x2 in fp64 (xor-reduce -> all lanes hold total)
  double x2 = 0.0;
#pragma unroll
  for (int j = 0; j < 4; ++j)
    x2 += (double)xv[j].x * xv[j].x + (double)xv[j].y * xv[j].y +
          (double)xv[j].z * xv[j].z + (double)xv[j].w * xv[j].w;
#pragma unroll
  for (int msk = 1; msk < 64; msk <<= 1) x2 += __shfl_xor(x2, msk, 64);

  // global max key -> margin threshold (fp8 dot err rms ~0.05; 0.35 >= 5 sigma)
  uint32_t m = max(kp.x, kp.z);
#pragma unroll
  for (int msk = 1; msk < 64; msk <<= 1)
    m = max(m, (uint32_t)__shfl_xor((int)m, msk, 64));
  const uint32_t thrk = packkey(unpackval(m) - 0.35f, 0);

  unsigned long long cand[4];
  cand[0] = __ballot(kp.x >= thrk);
  cand[1] = __ballot(kp.y >= thrk);
  cand[2] = __ballot(kp.z >= thrk);
  cand[3] = __ballot(kp.w >= thrk);

  double best = 1e300;
  int bestc = 0x7fffffff;
#pragma unroll 1
  for (int pass = 0; pass < 4; ++pass) {
    unsigned long long bits = cand[pass];
    uint32_t mykey = (pass == 0) ? kp.x : (pass == 1) ? kp.y
                    : (pass == 2) ? kp.z : kp.w;
    while (bits) {
      int tt = __ffsll((long long)bits) - 1;   // candidate's tile = lane tt
      bits &= bits - 1;
      uint32_t kbt = (uint32_t)__shfl((int)mykey, tt, 64);
      int col = tt * 128 + (int)(kbt & 127u);
      const float4* k4 = (const float4*)(kw + (size_t)col * DD);
      double dot = 0.0, w2 = 0.0;
#pragma unroll
      for (int j = 0; j < 4; ++j) {
        float4 wv = k4[L + 64 * j];
        dot += (double)xv[j].x * wv.x + (double)xv[j].y * wv.y +
               (double)xv[j].z * wv.z + (double)xv[j].w * wv.w;
        w2 += (double)wv.x * wv.x + (double)wv.y * wv.y +
              (double)wv.z * wv.z + (double)wv.w * wv.w;
      }
#pragma unroll
      for (int msk = 1; msk < 64; msk <<= 1) {
        dot += __shfl_xor(dot, msk, 64);
        w2 += __shfl_xor(w2, msk, 64);
      }
      double sq = x2 + w2 - 2.0 * dot;   // identical on all lanes
      if (sq < best || (sq == best && col < bestc)) { best = sq; bestc = col; }
    }
  }

  if (L == 0) out_w[b] = (float)bestc;  // winners as fp32 (flat fp32 buffer)
  if (Gt != nullptr) {
    // coalesced gather: out[b,:] = Gt[bestc,:]  (wave-uniform bestc)
    const float4* gsrc = (const float4*)(Gt + (size_t)bestc * OO);
    float4* gdst = (float4*)(out + (size_t)b * OO);
#pragma unroll
    for (int j = 0; j < 4; ++j) {
      int q = L + 64 * j;
      if (q < OO / 4) gdst[q] = gsrc[q];
    }
  } else {
    // fallback: strided gather from G
#pragma unroll 1
    for (int j = 0; j < 16; ++j) {
      int o = L + 64 * j;
      if (o < OO) out[(size_t)b * OO + o] = G[(size_t)o * HH + bestc];
    }
  }
}

extern "C" void kernel_launch(void* const* d_in, const int* in_sizes, int n_in,
                              void* d_out, int out_size, void* d_ws, size_t ws_size,
                              hipStream_t stream) {
  const float* x  = (const float*)d_in[0];  // [4096][1024]
  const float* kw = (const float*)d_in[1];  // [8192][1024]
  const float* gw = (const float*)d_in[2];  // [1000][8192]
  float* out = (float*)d_out;               // [4096*1000] output ++ [4096] winners
  float* out_w = out + (size_t)BB * OO;

  const size_t MB = 1024 * 1024;
  char* ws = (char*)d_ws;
  uint8_t* xq = (uint8_t*)(ws);             // 4 MB
  uint8_t* kq = (uint8_t*)(ws + 4 * MB);    // 8 MB
  uint4*   pk = (uint4*)(ws + 12 * MB);     // 4 MB
  float*   Gt = (float*)(ws + 16 * MB);     // 32.77 MB
  const size_t need = 16 * MB + sizeof(float) * (size_t)HH * OO;
  float* GtArg = (ws_size >= need) ? Gt : nullptr;

  // 1) fp32 -> fp8 e4m3 (4 rows/block) + parallel G transpose tiles
  int cvt_blocks = (BB + HH) / 4 + (GtArg ? 2048 : 0);
  cvt_kernel<<<cvt_blocks, 256, 0, stream>>>(x, kw, xq, kq, gw, GtArg);

  // 2) fp8 MFMA GEMM + top-2 keys per 64-col half
  dim3 g(HH / BN, BB / BM);  // (64, 32)
  gemm_top2<<<g, 256, 0, stream>>>(xq, kq, pk);

  // 3) wave-per-row exact fp64 refinement -> winners, fused coalesced gather
  select_kernel<<<BB / 4, 256, 0, stream>>>(x, kw, pk, GtArg, gw, out, out_w);
}